// Round 7
// baseline (687.273 us; speedup 1.0000x reference)
//
#include <hip/hip_runtime.h>
#include <hip/hip_fp16.h>

constexpr int N    = 100000;
constexpr int E    = 1600000;
constexpr int FIN  = 9;
constexpr int OUTF = 6;
constexpr int G    = 1024;
constexpr int NPB  = 256;                    // nodes per bucket
constexpr int NB   = (N + NPB - 1) / NPB;    // 391 buckets
constexpr int CH   = 2048;                   // edges per chunk
constexpr int NCH  = (E + CH - 1) / CH;      // 782
constexpr int BCAP = 4864;                   // arena slots/bucket (Poisson(4096)+12 sigma)
constexpr int CBCAP= BCAP + NPB + 8;         // csr slots/bucket = 5128
constexpr int EBUF = 5888;                   // passB LDS edge stash (>= BCAP)
constexpr int ZCNT = 256 + G * 64;           // stats0+stats1+pool floats to zero

typedef _Float16 f16x8 __attribute__((ext_vector_type(8)));
typedef float    f32x4 __attribute__((ext_vector_type(4)));

__device__ __forceinline__ void atomAddF(float* p, float v) { unsafeAtomicAdd(p, v); }

__device__ __forceinline__ float us2f(unsigned short u) {
    return __half2float(__builtin_bit_cast(__half, u));
}

// async global->LDS staging, 4B/lane at wave-uniform LDS base + lane*4.
// Side-effecting intrinsic: compiler cannot sink/rematerialize it (the r4/r5 failure
// mode for plain loads) and never holds the in-flight data in a VGPR (the r6 crash).
__device__ __forceinline__ void gll4(const void* g, void* l) {
    __builtin_amdgcn_global_load_lds((const __attribute__((address_space(1))) void*)g,
                                     (__attribute__((address_space(3))) void*)l, 4, 0, 0);
}

// ---- init: arena cursors + zero stats/pool + x -> fp16 table ----
__global__ __launch_bounds__(256) void initK(int* __restrict__ cursor, float* __restrict__ zeros,
    const float* __restrict__ x, __half* __restrict__ x9)
{
    int i = blockIdx.x * 256 + threadIdx.x;
    if (i < NB) cursor[i] = i * BCAP;
    if (i < ZCNT) zeros[i] = 0.f;
    if (i < N * FIN) x9[i] = __float2half(x[i]);
}

// ---- CSR build pass 1: scatter packed edges (src | dloc<<24, w) into fixed-stride arena ----
__global__ __launch_bounds__(256) void passA(const int* __restrict__ src, const int* __restrict__ dst,
    const float* __restrict__ ew, int* __restrict__ cursor, int2* __restrict__ bucketed)
{
    __shared__ int h[NB];
    __shared__ int hb[NB];
    int t = threadIdx.x;
    for (int i = t; i < NB; i += 256) h[i] = 0;
    __syncthreads();
    int base = blockIdx.x * CH;
    int myS[8], myD[8], rk[8]; float myW[8];
#pragma unroll
    for (int i = 0; i < 8; i++) {
        int e = base + i * 256 + t;
        if (e < E) {
            myS[i] = src[e]; myD[i] = dst[e]; myW[i] = ew[e];
            rk[i] = atomicAdd(&h[myD[i] >> 8], 1);
        } else myD[i] = -1;
    }
    __syncthreads();
    for (int i = t; i < NB; i += 256) hb[i] = h[i] ? atomicAdd(&cursor[i], h[i]) : 0;
    __syncthreads();
#pragma unroll
    for (int i = 0; i < 8; i++) if (myD[i] >= 0) {
        int packed = myS[i] | ((myD[i] & 255) << 24);
        bucketed[hb[myD[i] >> 8] + rk[i]] = make_int2(packed, __float_as_int(myW[i]));
    }
}

// ---- CSR build pass 2: per-bucket local CSR (LDS stash), even-aligned node regions ----
__global__ __launch_bounds__(NPB) void passB(const int* __restrict__ cursor,
    const int2* __restrict__ bucketed, int* __restrict__ ebeg, int* __restrict__ eend,
    int2* __restrict__ csr)
{
    __shared__ int2 ebuf[EBUF];
    __shared__ int cl[NPB], sa[NPB], sb[NPB], curs[NPB];
    int b = blockIdx.x, t = threadIdx.x;
    int node0 = b * NPB;
    int nnode = min(NPB, N - node0);
    int cnt = cursor[b] - b * BCAP;
    int abase = b * BCAP;
    int base = b * CBCAP;
    bool fits = (cnt <= EBUF);
    cl[t] = 0;
    __syncthreads();
    for (int e = t; e < cnt; e += NPB) {
        int2 r = bucketed[abase + e];
        if (fits) ebuf[e] = r;
        atomicAdd(&cl[((unsigned)r.x) >> 24], 1);
    }
    __syncthreads();
    int deg = cl[t];
    int pc = (deg + 1) & ~1;
    int* cur = sa; int* nxt = sb;
    cur[t] = pc;
    __syncthreads();
    for (int o = 1; o < NPB; o <<= 1) {
        int v = cur[t];
        if (t >= o) v += cur[t - o];
        nxt[t] = v;
        __syncthreads();
        int* tmp = cur; cur = nxt; nxt = tmp;
    }
    int off = cur[t] - pc;
    if (t < nnode) { ebeg[node0 + t] = base + off; eend[node0 + t] = base + off + deg; }
    curs[t] = off;
    __syncthreads();
    for (int e = t; e < cnt; e += NPB) {
        int2 r = fits ? ebuf[e] : bucketed[abase + e];
        int dl = ((unsigned)r.x) >> 24;
        int pos = base + atomicAdd(&curs[dl], 1);
        csr[pos] = make_int2(r.x & 0x00FFFFFF, r.y);
    }
    __syncthreads();
    if (t < nnode && (deg & 1)) csr[base + off + deg] = make_int2(0, 0);   // w=0 pad
    if (t < 4) csr[base + cur[NPB - 1] + t] = make_int2(0, 0);             // tail pads
}

// ---- weight prep: Wt[c][k] fp16 for layers 1,2 ----
__global__ __launch_bounds__(256) void wprep(const float* __restrict__ Wrel1, const float* __restrict__ Wroot1,
    const float* __restrict__ Wrel2, const float* __restrict__ Wroot2, __half* __restrict__ Wt)
{
    int i = blockIdx.x * 256 + threadIdx.x;      // over 2*128*64 = 16384
    int layer = i >> 13, r = i & 8191;
    int c = r >> 6, k = r & 63;
    const float* Wrel = layer ? Wrel2 : Wrel1;
    const float* Wroot = layer ? Wroot2 : Wroot1;
    float v = (c < 64) ? Wrel[k * 64 + c] : Wroot[k * 64 + (c - 64)];
    Wt[i] = __float2half(v);
}

// ---- layer-0 gather in 9-dim, SOFTWARE-PIPELINED (2-stage csr/x9 rotation) ----
__global__ __launch_bounds__(256, 2) void gather9(const __half* __restrict__ x9h,
    const int2* __restrict__ csr, const int* __restrict__ ebeg, const int* __restrict__ eend,
    float* __restrict__ agg9)
{
    const unsigned short* __restrict__ x9 = (const unsigned short*)x9h;
    int t = threadIdx.x, lane = t & 63;
    int es = lane >> 4, fc = min(lane & 15, FIN - 1);
    int wv = __builtin_amdgcn_readfirstlane((blockIdx.x * blockDim.x + t) >> 6);
    int nw = (gridDim.x * blockDim.x) >> 6;
    for (int n = wv; n < N; n += nw) {
        int beg = ebeg[n], end = eend[n];
        int last = end - 1;
        int2 eA0 = csr[min(beg + es,      last)];
        int2 eB0 = csr[min(beg + 4 + es,  last)];
        int2 eA1 = csr[min(beg + 8 + es,  last)];
        int2 eB1 = csr[min(beg + 12 + es, last)];
        unsigned short xA = x9[(size_t)eA0.x * FIN + fc];
        unsigned short xB = x9[(size_t)eB0.x * FIN + fc];
        float a0 = 0.f, a1 = 0.f;
        for (int k = beg; k < end; k += 8) {
            int2 eA2 = csr[min(k + 16 + es, last)];
            int2 eB2 = csr[min(k + 20 + es, last)];
            unsigned short nxA = x9[(size_t)eA1.x * FIN + fc];
            unsigned short nxB = x9[(size_t)eB1.x * FIN + fc];
            float wA = (k + es     < end) ? __int_as_float(eA0.y) : 0.f;
            float wB = (k + 4 + es < end) ? __int_as_float(eB0.y) : 0.f;
            a0 = fmaf(wA, us2f(xA), a0);
            a1 = fmaf(wB, us2f(xB), a1);
            eA0 = eA1; eB0 = eB1; eA1 = eA2; eB1 = eB2;
            xA = nxA; xB = nxB;
        }
        float r = a0 + a1;
        r += __shfl(r, lane ^ 16, 64);
        r += __shfl(r, lane ^ 32, 64);
        if (lane < FIN) agg9[(size_t)n * FIN + lane] = r;
    }
}

// ---- layer-0 projection (post-gather): H0 = agg9@Wrel0 + x@Wroot0 + b0 ; BN stats ----
__global__ __launch_bounds__(256) void proj0post(const float* __restrict__ x,
    const float* __restrict__ agg9, const float* __restrict__ Wrel,
    const float* __restrict__ Wroot, const float* __restrict__ bias,
    __half* __restrict__ H0, float* __restrict__ stats)
{
    int t = threadIdx.x, j = t & 63;
    int nl = __builtin_amdgcn_readfirstlane(t >> 6);
    float wrel[FIN], wroot[FIN];
#pragma unroll
    for (int k = 0; k < FIN; k++) { wrel[k] = Wrel[k * 64 + j]; wroot[k] = Wroot[k * 64 + j]; }
    float bj = bias[j];
    float s1 = 0.f, s2 = 0.f;
    const int ntiles = N / 4;
    for (int tile = blockIdx.x; tile < ntiles; tile += gridDim.x) {
        int n = tile * 4 + nl;
        const float* xr = x + (size_t)n * FIN;
        const float* ar = agg9 + (size_t)n * FIN;
        float acc = bj;
#pragma unroll
        for (int k = 0; k < FIN; k++) {
            acc = fmaf(ar[k], wrel[k], acc);
            acc = fmaf(xr[k], wroot[k], acc);
        }
        H0[(size_t)n * 64 + j] = __float2half(acc);
        s1 += acc; s2 += acc * acc;
    }
    __shared__ float sred[256];
    sred[t] = s1; __syncthreads();
    if (t < 64) atomAddF(&stats[t], sred[t] + sred[t+64] + sred[t+128] + sred[t+192]);
    __syncthreads();
    sred[t] = s2; __syncthreads();
    if (t < 64) atomAddF(&stats[64 + t], sred[t] + sred[t+64] + sred[t+128] + sred[t+192]);
}

// ---- MFMA projection w/ fused BN+ReLU on input ----
__global__ __launch_bounds__(256) void projm(const __half* __restrict__ Hin, const __half* __restrict__ Wt,
    const float* __restrict__ bias, const float* __restrict__ stats,
    const float* __restrict__ gam, const float* __restrict__ bet,
    __half* __restrict__ P, __half* __restrict__ Hout)
{
    int t = threadIdx.x, lane = t & 63;
    int wv = blockIdx.x * 4 + (t >> 6);
    int nw = gridDim.x * 4;
    int n16 = lane & 15, quad = lane >> 4;
    constexpr float invN = 1.0f / (float)N;
    float sc[16], sh[16];
#pragma unroll
    for (int jj = 0; jj < 16; jj++) {
        int k = (jj < 8) ? (quad * 8 + jj) : (32 + quad * 8 + (jj - 8));
        float m = stats[k] * invN;
        float v = stats[64 + k] * invN - m * m;
        sc[jj] = gam[k] * rsqrtf(v + 1e-5f);
        sh[jj] = bet[k] - m * sc[jj];
    }
    f16x8 bf[8][2];
#pragma unroll
    for (int ct = 0; ct < 8; ct++)
#pragma unroll
        for (int kh = 0; kh < 2; kh++)
            bf[ct][kh] = *(const f16x8*)(Wt + (size_t)(ct * 16 + n16) * 64 + kh * 32 + quad * 8);
    float bcol[4];
#pragma unroll
    for (int i = 0; i < 4; i++) bcol[i] = bias[i * 16 + n16];
    const int NT = N / 16;
    for (int tile = wv; tile < NT; tile += nw) {
        int n0 = tile * 16;
        f16x8 r0 = *(const f16x8*)(Hin + (size_t)(n0 + n16) * 64 + quad * 8);
        f16x8 r1 = *(const f16x8*)(Hin + (size_t)(n0 + n16) * 64 + 32 + quad * 8);
        f16x8 a0, a1;
#pragma unroll
        for (int jj = 0; jj < 8; jj++) {
            a0[jj] = (_Float16)fmaxf(fmaf((float)r0[jj], sc[jj],     sh[jj]),     0.f);
            a1[jj] = (_Float16)fmaxf(fmaf((float)r1[jj], sc[jj + 8], sh[jj + 8]), 0.f);
        }
        f32x4 acc[8];
#pragma unroll
        for (int ct = 0; ct < 8; ct++) {
            f32x4 c = {0.f, 0.f, 0.f, 0.f};
            c = __builtin_amdgcn_mfma_f32_16x16x32_f16(a0, bf[ct][0], c, 0, 0, 0);
            c = __builtin_amdgcn_mfma_f32_16x16x32_f16(a1, bf[ct][1], c, 0, 0, 0);
            acc[ct] = c;
        }
#pragma unroll
        for (int ct = 0; ct < 8; ct++) {
#pragma unroll
            for (int r = 0; r < 4; r++) {
                int n = n0 + quad * 4 + r;
                if (ct < 4) P[(size_t)n * 64 + ct * 16 + n16] = __float2half(acc[ct][r]);
                else Hout[(size_t)n * 64 + (ct - 4) * 16 + n16] = __float2half(acc[ct][r] + bcol[ct - 4]);
            }
        }
    }
}

// ---- gather via global_load_lds ring pipeline ----
// Quantum = 1 int4-packet pair = 4 edges = 4 P rows, staged by 2 gll4 (256B each).
// Ring: 8 slots x 512B per wave. Lookahead 4 quanta => vmcnt(8) gates the oldest.
// In-flight state lives in LDS + HW queue, NOT VGPRs: immune to compiler sinking
// (r4/r5) and to the in-flight-register-copy crash (r6).
constexpr int GLK = 4;     // lookahead quanta
constexpr int GRS = 8;     // ring slots (pow2 > GLK)

template<int EPI>   // 0: write H + BN stats; 1: pool atomics
__global__ __launch_bounds__(256) void gather(const __half* __restrict__ Ph, __half* H,
    const int2* __restrict__ csr, const int* __restrict__ ebeg, const int* __restrict__ eend,
    float* __restrict__ stats, const int* __restrict__ batch, float* __restrict__ pool)
{
    __shared__ unsigned short ring[4][GRS][256];   // 4 waves x 8 slots x 512B = 16KB
    __shared__ int4 pring[4][GRS][2];              // staged csr packets, 1KB
    __shared__ float sred[256];
    int t = threadIdx.x, lane = t & 63, w = t >> 6;
    unsigned short* myring = &ring[w][0][0];
    int4* mypring = &pring[w][0][0];
    const char* Pb = (const char*)Ph;
    const int4* csr4 = (const int4*)csr;
    int wv = __builtin_amdgcn_readfirstlane((blockIdx.x * blockDim.x + t) >> 6);
    int nw = (gridDim.x * blockDim.x) >> 6;
    int l31 = (lane & 31) * 4;

    // producer state (runs GLK quanta ahead of the consumer)
    int pn = pn = wv, ppb = 0, ppm = 0, pnq = 0, pq = 0;
    {
        int b = ebeg[pn]; ppb = b >> 1; ppm = (eend[pn] - b + 1) >> 1; pnq = (ppm + 1) >> 1;
        while (pnq == 0) {
            pn += nw; if (pn >= N) break;
            int b2 = ebeg[pn]; ppb = b2 >> 1; ppm = (eend[pn] - b2 + 1) >> 1; pnq = (ppm + 1) >> 1;
        }
    }
    auto produceStep = [&](int slot) {
        if (pn < N) {
            int lastpk = ppb + ppm - 1;
            int4 pk0 = csr4[min(ppb + 2 * pq,     lastpk)];
            int4 pk1 = csr4[min(ppb + 2 * pq + 1, lastpk)];
            int r0 = (lane < 32) ? pk0.x : pk0.z;
            int r1 = (lane < 32) ? pk1.x : pk1.z;
            gll4(Pb + (size_t)r0 * 128 + l31, myring + slot * 256);        // rows 0,1
            gll4(Pb + (size_t)r1 * 128 + l31, myring + slot * 256 + 128);  // rows 2,3
            if (lane < 2) mypring[slot * 2 + lane] = lane ? pk1 : pk0;
            pq++;
            if (pq >= pnq) {
                pq = 0;
                do {
                    pn += nw; if (pn >= N) break;
                    int b = ebeg[pn]; ppb = b >> 1; ppm = (eend[pn] - b + 1) >> 1; pnq = (ppm + 1) >> 1;
                } while (pnq == 0);
            }
        } else {
            // dummy counted issues keep vmcnt arithmetic exact at the tail
            gll4(Pb + l31, myring + slot * 256);
            gll4(Pb + l31, myring + slot * 256 + 128);
        }
    };

    int qp = 0, qc = 0;
    for (int i = 0; i < GLK; i++) { produceStep(qp & (GRS - 1)); qp++; }

    float s1 = 0.f, s2 = 0.f;
    for (int cn = wv; cn < N; cn += nw) {
        int b = ebeg[cn];
        int cm = (eend[cn] - b + 1) >> 1;      // int4 packet count
        int cnq = (cm + 1) >> 1;               // quanta
        float xr = __half2float(H[(size_t)cn * 64 + lane]);
        float acc = 0.f;
        for (int q = 0; q < cnq; q++) {
            produceStep(qp & (GRS - 1)); qp++;
            int slot = qc & (GRS - 1); qc++;
            // oldest quantum retired when <=8 newer counted loads remain outstanding;
            // uncounted compiler VMEM issued after it only inflates the margin (safe).
            asm volatile("s_waitcnt vmcnt(8)" ::: "memory");
            int4 pk0 = mypring[slot * 2];
            int4 pk1 = mypring[slot * 2 + 1];
            const unsigned short* s = myring + slot * 256;
            float v0 = us2f(s[lane]);
            float v1 = us2f(s[64 + lane]);
            float v2 = us2f(s[128 + lane]);
            float v3 = us2f(s[192 + lane]);
            float w0 = (2 * q     < cm) ? __int_as_float(pk0.y) : 0.f;
            float w1 = (2 * q     < cm) ? __int_as_float(pk0.w) : 0.f;
            float w2 = (2 * q + 1 < cm) ? __int_as_float(pk1.y) : 0.f;
            float w3 = (2 * q + 1 < cm) ? __int_as_float(pk1.w) : 0.f;
            acc = fmaf(w0, v0, acc);
            acc = fmaf(w1, v1, acc);
            acc = fmaf(w2, v2, acc);
            acc = fmaf(w3, v3, acc);
        }
        float r = xr + acc;
        if constexpr (EPI == 0) {
            H[(size_t)cn * 64 + lane] = __float2half(r);
            s1 += r; s2 += r * r;
        } else {
            atomAddF(&pool[batch[cn] * 64 + lane], r);
        }
    }
    asm volatile("s_waitcnt vmcnt(0)" ::: "memory");   // drain tail before wave exit

    if constexpr (EPI == 0) {
        sred[t] = s1; __syncthreads();
        if (t < 64) atomAddF(&stats[t], sred[t] + sred[t+64] + sred[t+128] + sred[t+192]);
        __syncthreads();
        sred[t] = s2; __syncthreads();
        if (t < 64) atomAddF(&stats[64 + t], sred[t] + sred[t+64] + sred[t+128] + sred[t+192]);
    }
}

// ---- head: mean-pool finalize + 2-layer MLP ----
__global__ __launch_bounds__(64) void head(const float* __restrict__ pool,
    const int* __restrict__ batch, const float* __restrict__ Wl1, const float* __restrict__ bl1,
    const float* __restrict__ Wl2, const float* __restrict__ bl2, float* __restrict__ out)
{
    int g = blockIdx.x, t = threadIdx.x;
    __shared__ float sp[64];
    __shared__ float sz[64];
    __shared__ int scnt;
    if (t == 0) {
        int lo = 0, hi = N;
        while (lo < hi) { int m = (lo + hi) >> 1; if (batch[m] < g) lo = m + 1; else hi = m; }
        int lo2 = lo, hi2 = N;
        while (lo2 < hi2) { int m = (lo2 + hi2) >> 1; if (batch[m] < g + 1) lo2 = m + 1; else hi2 = m; }
        scnt = lo2 - lo;
    }
    __syncthreads();
    float cnt = fmaxf((float)scnt, 1.0f);
    sp[t] = pool[g * 64 + t] / cnt;
    __syncthreads();
    float acc = bl1[t];
#pragma unroll
    for (int k = 0; k < 64; k++) acc = fmaf(sp[k], Wl1[k * 64 + t], acc);
    sz[t] = fmaxf(acc, 0.f);
    __syncthreads();
    if (t < OUTF) {
        float o = bl2[t];
#pragma unroll
        for (int k = 0; k < 64; k++) o = fmaf(sz[k], Wl2[k * OUTF + t], o);
        out[g * OUTF + t] = o;
    }
}

extern "C" void kernel_launch(void* const* d_in, const int* in_sizes, int n_in,
                              void* d_out, int out_size, void* d_ws, size_t ws_size,
                              hipStream_t stream)
{
    const float* x     = (const float*)d_in[0];
    const int*   ei    = (const int*)d_in[1];
    const float* ew    = (const float*)d_in[2];
    const int*   batch = (const int*)d_in[3];
    const float* Wrel0 = (const float*)d_in[4];
    const float* Wroot0= (const float*)d_in[5];
    const float* b0    = (const float*)d_in[6];
    const float* Wrel1 = (const float*)d_in[7];
    const float* Wroot1= (const float*)d_in[8];
    const float* b1    = (const float*)d_in[9];
    const float* Wrel2 = (const float*)d_in[10];
    const float* Wroot2= (const float*)d_in[11];
    const float* b2    = (const float*)d_in[12];
    const float* g0    = (const float*)d_in[13];
    const float* be0   = (const float*)d_in[14];
    const float* g1    = (const float*)d_in[15];
    const float* be1   = (const float*)d_in[16];
    const float* Wl1   = (const float*)d_in[17];
    const float* bl1   = (const float*)d_in[18];
    const float* Wl2   = (const float*)d_in[19];
    const float* bl2   = (const float*)d_in[20];
    const int* srcI = ei;
    const int* dstI = ei + E;

    __half* Ha     = (__half*)d_ws;                    // N*64 fp16
    __half* Hb     = Ha + (size_t)N * 64;              // N*64 fp16
    __half* P      = Hb + (size_t)N * 64;              // N*64 fp16
    int2*   csr    = (int2*)(P + (size_t)N * 64);      // NB*CBCAP int2 (~16 MB)
    int*    ebeg   = (int*)(csr + (size_t)NB * CBCAP); // N
    int*    eend   = ebeg + N;                         // N
    int*    cursor = eend + N;                         // NB
    float*  stats0 = (float*)(cursor + NB);            // 128 -- zero block start
    float*  stats1 = stats0 + 128;                     // 128
    float*  pool   = stats1 + 128;                     // G*64 -- zero block end
    __half* Wt1    = (__half*)(pool + G * 64);         // 128*64
    __half* Wt2    = Wt1 + 128 * 64;                   // 128*64
    float*  agg9   = (float*)(Wt2 + 128 * 64);         // N*9 f32 (3.6 MB)
    __half* x9     = (__half*)(agg9 + (size_t)N * FIN);// N*9 fp16 (1.8 MB)
    int2*   bucketed = (int2*)Ha;                      // NB*BCAP int2 = 15.2MB, aliases Ha+Hb

    // ---- init + CSR build (bucketed arena, by dst) ----
    initK<<<(N * FIN + 255) / 256, 256, 0, stream>>>(cursor, stats0, x, x9);
    passA<<<NCH, 256, 0, stream>>>(srcI, dstI, ew, cursor, bucketed);
    passB<<<NB, NPB, 0, stream>>>(cursor, bucketed, ebeg, eend, csr);
    wprep<<<64, 256, 0, stream>>>(Wrel1, Wroot1, Wrel2, Wroot2, Wt1);

    // ---- layer 0: 9-dim gather (pipelined) then projection ----
    gather9<<<2048, 256, 0, stream>>>(x9, csr, ebeg, eend, agg9);
    proj0post<<<2048, 256, 0, stream>>>(x, agg9, Wrel0, Wroot0, b0, Ha, stats0);

    // ---- layer 1 (BN0+ReLU fused into projm input) ----
    projm<<<1024, 256, 0, stream>>>(Ha, Wt1, b1, stats0, g0, be0, P, Hb);
    gather<0><<<2048, 256, 0, stream>>>(P, Hb, csr, ebeg, eend, stats1, nullptr, nullptr);

    // ---- layer 2 + pooling (BN1+ReLU fused into projm input) ----
    projm<<<1024, 256, 0, stream>>>(Hb, Wt2, b2, stats1, g1, be1, P, Ha);
    gather<1><<<2048, 256, 0, stream>>>(P, Ha, csr, ebeg, eend, nullptr, batch, pool);

    // ---- head ----
    head<<<G, 64, 0, stream>>>(pool, batch, Wl1, bl1, Wl2, bl2, (float*)d_out);
}

// Round 8
// 443.070 us; speedup vs baseline: 1.5512x; 1.5512x over previous
//
#include <hip/hip_runtime.h>
#include <hip/hip_fp16.h>

constexpr int N    = 100000;
constexpr int E    = 1600000;
constexpr int FIN  = 9;
constexpr int OUTF = 6;
constexpr int G    = 1024;
constexpr int NPB  = 256;                    // nodes per bucket
constexpr int NB   = (N + NPB - 1) / NPB;    // 391 buckets
constexpr int CH   = 2048;                   // edges per chunk
constexpr int NCH  = (E + CH - 1) / CH;      // 782
constexpr int BCAP = 4864;                   // arena slots/bucket (Poisson(4096)+12 sigma)
constexpr int CBCAP= BCAP + NPB + 8;         // csr slots/bucket = 5128
constexpr int EBUF = 5888;                   // passB LDS edge stash (>= BCAP)
constexpr int ZCNT = 256 + G * 64;           // stats0+stats1+pool floats to zero

typedef _Float16 f16x8 __attribute__((ext_vector_type(8)));
typedef float    f32x4 __attribute__((ext_vector_type(4)));

__device__ __forceinline__ void atomAddF(float* p, float v) { unsafeAtomicAdd(p, v); }

__device__ __forceinline__ float us2f(unsigned short u) {
    return __half2float(__builtin_bit_cast(__half, u));
}

// ---- init: arena cursors + zero stats/pool + x -> fp16 table ----
__global__ __launch_bounds__(256) void initK(int* __restrict__ cursor, float* __restrict__ zeros,
    const float* __restrict__ x, __half* __restrict__ x9)
{
    int i = blockIdx.x * 256 + threadIdx.x;
    if (i < NB) cursor[i] = i * BCAP;
    if (i < ZCNT) zeros[i] = 0.f;
    if (i < N * FIN) x9[i] = __float2half(x[i]);
}

// ---- CSR build pass 1: scatter packed edges (src | dloc<<24, w) into fixed-stride arena ----
__global__ __launch_bounds__(256) void passA(const int* __restrict__ src, const int* __restrict__ dst,
    const float* __restrict__ ew, int* __restrict__ cursor, int2* __restrict__ bucketed)
{
    __shared__ int h[NB];
    __shared__ int hb[NB];
    int t = threadIdx.x;
    for (int i = t; i < NB; i += 256) h[i] = 0;
    __syncthreads();
    int base = blockIdx.x * CH;
    int myS[8], myD[8], rk[8]; float myW[8];
#pragma unroll
    for (int i = 0; i < 8; i++) {
        int e = base + i * 256 + t;
        if (e < E) {
            myS[i] = src[e]; myD[i] = dst[e]; myW[i] = ew[e];
            rk[i] = atomicAdd(&h[myD[i] >> 8], 1);
        } else myD[i] = -1;
    }
    __syncthreads();
    for (int i = t; i < NB; i += 256) hb[i] = h[i] ? atomicAdd(&cursor[i], h[i]) : 0;
    __syncthreads();
#pragma unroll
    for (int i = 0; i < 8; i++) if (myD[i] >= 0) {
        int packed = myS[i] | ((myD[i] & 255) << 24);
        bucketed[hb[myD[i] >> 8] + rk[i]] = make_int2(packed, __float_as_int(myW[i]));
    }
}

// ---- CSR build pass 2: per-bucket local CSR (LDS stash), even-aligned node regions ----
__global__ __launch_bounds__(NPB) void passB(const int* __restrict__ cursor,
    const int2* __restrict__ bucketed, int* __restrict__ ebeg, int* __restrict__ eend,
    int2* __restrict__ csr)
{
    __shared__ int2 ebuf[EBUF];
    __shared__ int cl[NPB], sa[NPB], sb[NPB], curs[NPB];
    int b = blockIdx.x, t = threadIdx.x;
    int node0 = b * NPB;
    int nnode = min(NPB, N - node0);
    int cnt = cursor[b] - b * BCAP;
    int abase = b * BCAP;
    int base = b * CBCAP;
    bool fits = (cnt <= EBUF);
    cl[t] = 0;
    __syncthreads();
    for (int e = t; e < cnt; e += NPB) {
        int2 r = bucketed[abase + e];
        if (fits) ebuf[e] = r;
        atomicAdd(&cl[((unsigned)r.x) >> 24], 1);
    }
    __syncthreads();
    int deg = cl[t];
    int pc = (deg + 1) & ~1;
    int* cur = sa; int* nxt = sb;
    cur[t] = pc;
    __syncthreads();
    for (int o = 1; o < NPB; o <<= 1) {
        int v = cur[t];
        if (t >= o) v += cur[t - o];
        nxt[t] = v;
        __syncthreads();
        int* tmp = cur; cur = nxt; nxt = tmp;
    }
    int off = cur[t] - pc;
    if (t < nnode) { ebeg[node0 + t] = base + off; eend[node0 + t] = base + off + deg; }
    curs[t] = off;
    __syncthreads();
    for (int e = t; e < cnt; e += NPB) {
        int2 r = fits ? ebuf[e] : bucketed[abase + e];
        int dl = ((unsigned)r.x) >> 24;
        int pos = base + atomicAdd(&curs[dl], 1);
        csr[pos] = make_int2(r.x & 0x00FFFFFF, r.y);
    }
    __syncthreads();
    if (t < nnode && (deg & 1)) csr[base + off + deg] = make_int2(0, 0);   // w=0 pad
    if (t < 4) csr[base + cur[NPB - 1] + t] = make_int2(0, 0);             // tail pads
}

// ---- weight prep: Wt[c][k] fp16 for layers 1,2 ----
__global__ __launch_bounds__(256) void wprep(const float* __restrict__ Wrel1, const float* __restrict__ Wroot1,
    const float* __restrict__ Wrel2, const float* __restrict__ Wroot2, __half* __restrict__ Wt)
{
    int i = blockIdx.x * 256 + threadIdx.x;      // over 2*128*64 = 16384
    int layer = i >> 13, r = i & 8191;
    int c = r >> 6, k = r & 63;
    const float* Wrel = layer ? Wrel2 : Wrel1;
    const float* Wroot = layer ? Wroot2 : Wroot1;
    float v = (c < 64) ? Wrel[k * 64 + c] : Wroot[k * 64 + (c - 64)];
    Wt[i] = __float2half(v);
}

// ---- layer-0 gather in 9-dim, SOFTWARE-PIPELINED (2-stage csr/x9 rotation) ----
__global__ __launch_bounds__(256, 2) void gather9(const __half* __restrict__ x9h,
    const int2* __restrict__ csr, const int* __restrict__ ebeg, const int* __restrict__ eend,
    float* __restrict__ agg9)
{
    const unsigned short* __restrict__ x9 = (const unsigned short*)x9h;
    int t = threadIdx.x, lane = t & 63;
    int es = lane >> 4, fc = min(lane & 15, FIN - 1);
    int wv = __builtin_amdgcn_readfirstlane((blockIdx.x * blockDim.x + t) >> 6);
    int nw = (gridDim.x * blockDim.x) >> 6;
    for (int n = wv; n < N; n += nw) {
        int beg = ebeg[n], end = eend[n];
        int last = end - 1;
        int2 eA0 = csr[min(beg + es,      last)];
        int2 eB0 = csr[min(beg + 4 + es,  last)];
        int2 eA1 = csr[min(beg + 8 + es,  last)];
        int2 eB1 = csr[min(beg + 12 + es, last)];
        unsigned short xA = x9[(size_t)eA0.x * FIN + fc];
        unsigned short xB = x9[(size_t)eB0.x * FIN + fc];
        float a0 = 0.f, a1 = 0.f;
        for (int k = beg; k < end; k += 8) {
            int2 eA2 = csr[min(k + 16 + es, last)];
            int2 eB2 = csr[min(k + 20 + es, last)];
            unsigned short nxA = x9[(size_t)eA1.x * FIN + fc];
            unsigned short nxB = x9[(size_t)eB1.x * FIN + fc];
            float wA = (k + es     < end) ? __int_as_float(eA0.y) : 0.f;
            float wB = (k + 4 + es < end) ? __int_as_float(eB0.y) : 0.f;
            a0 = fmaf(wA, us2f(xA), a0);
            a1 = fmaf(wB, us2f(xB), a1);
            eA0 = eA1; eB0 = eB1; eA1 = eA2; eB1 = eB2;
            xA = nxA; xB = nxB;
        }
        float r = a0 + a1;
        r += __shfl(r, lane ^ 16, 64);
        r += __shfl(r, lane ^ 32, 64);
        if (lane < FIN) agg9[(size_t)n * FIN + lane] = r;
    }
}

// ---- layer-0 projection (post-gather): H0 = agg9@Wrel0 + x@Wroot0 + b0 ; BN stats ----
__global__ __launch_bounds__(256) void proj0post(const float* __restrict__ x,
    const float* __restrict__ agg9, const float* __restrict__ Wrel,
    const float* __restrict__ Wroot, const float* __restrict__ bias,
    __half* __restrict__ H0, float* __restrict__ stats)
{
    int t = threadIdx.x, j = t & 63;
    int nl = __builtin_amdgcn_readfirstlane(t >> 6);
    float wrel[FIN], wroot[FIN];
#pragma unroll
    for (int k = 0; k < FIN; k++) { wrel[k] = Wrel[k * 64 + j]; wroot[k] = Wroot[k * 64 + j]; }
    float bj = bias[j];
    float s1 = 0.f, s2 = 0.f;
    const int ntiles = N / 4;
    for (int tile = blockIdx.x; tile < ntiles; tile += gridDim.x) {
        int n = tile * 4 + nl;
        const float* xr = x + (size_t)n * FIN;
        const float* ar = agg9 + (size_t)n * FIN;
        float acc = bj;
#pragma unroll
        for (int k = 0; k < FIN; k++) {
            acc = fmaf(ar[k], wrel[k], acc);
            acc = fmaf(xr[k], wroot[k], acc);
        }
        H0[(size_t)n * 64 + j] = __float2half(acc);
        s1 += acc; s2 += acc * acc;
    }
    __shared__ float sred[256];
    sred[t] = s1; __syncthreads();
    if (t < 64) atomAddF(&stats[t], sred[t] + sred[t+64] + sred[t+128] + sred[t+192]);
    __syncthreads();
    sred[t] = s2; __syncthreads();
    if (t < 64) atomAddF(&stats[64 + t], sred[t] + sred[t+64] + sred[t+128] + sred[t+192]);
}

// ---- MFMA projection w/ fused BN+ReLU on input ----
__global__ __launch_bounds__(256) void projm(const __half* __restrict__ Hin, const __half* __restrict__ Wt,
    const float* __restrict__ bias, const float* __restrict__ stats,
    const float* __restrict__ gam, const float* __restrict__ bet,
    __half* __restrict__ P, __half* __restrict__ Hout)
{
    int t = threadIdx.x, lane = t & 63;
    int wv = blockIdx.x * 4 + (t >> 6);
    int nw = gridDim.x * 4;
    int n16 = lane & 15, quad = lane >> 4;
    constexpr float invN = 1.0f / (float)N;
    float sc[16], sh[16];
#pragma unroll
    for (int jj = 0; jj < 16; jj++) {
        int k = (jj < 8) ? (quad * 8 + jj) : (32 + quad * 8 + (jj - 8));
        float m = stats[k] * invN;
        float v = stats[64 + k] * invN - m * m;
        sc[jj] = gam[k] * rsqrtf(v + 1e-5f);
        sh[jj] = bet[k] - m * sc[jj];
    }
    f16x8 bf[8][2];
#pragma unroll
    for (int ct = 0; ct < 8; ct++)
#pragma unroll
        for (int kh = 0; kh < 2; kh++)
            bf[ct][kh] = *(const f16x8*)(Wt + (size_t)(ct * 16 + n16) * 64 + kh * 32 + quad * 8);
    float bcol[4];
#pragma unroll
    for (int i = 0; i < 4; i++) bcol[i] = bias[i * 16 + n16];
    const int NT = N / 16;
    for (int tile = wv; tile < NT; tile += nw) {
        int n0 = tile * 16;
        f16x8 r0 = *(const f16x8*)(Hin + (size_t)(n0 + n16) * 64 + quad * 8);
        f16x8 r1 = *(const f16x8*)(Hin + (size_t)(n0 + n16) * 64 + 32 + quad * 8);
        f16x8 a0, a1;
#pragma unroll
        for (int jj = 0; jj < 8; jj++) {
            a0[jj] = (_Float16)fmaxf(fmaf((float)r0[jj], sc[jj],     sh[jj]),     0.f);
            a1[jj] = (_Float16)fmaxf(fmaf((float)r1[jj], sc[jj + 8], sh[jj + 8]), 0.f);
        }
        f32x4 acc[8];
#pragma unroll
        for (int ct = 0; ct < 8; ct++) {
            f32x4 c = {0.f, 0.f, 0.f, 0.f};
            c = __builtin_amdgcn_mfma_f32_16x16x32_f16(a0, bf[ct][0], c, 0, 0, 0);
            c = __builtin_amdgcn_mfma_f32_16x16x32_f16(a1, bf[ct][1], c, 0, 0, 0);
            acc[ct] = c;
        }
#pragma unroll
        for (int ct = 0; ct < 8; ct++) {
#pragma unroll
            for (int r = 0; r < 4; r++) {
                int n = n0 + quad * 4 + r;
                if (ct < 4) P[(size_t)n * 64 + ct * 16 + n16] = __float2half(acc[ct][r]);
                else Hout[(size_t)n * 64 + (ct - 4) * 16 + n16] = __float2half(acc[ct][r] + bcol[ct - 4]);
            }
        }
    }
}

// ---- gather-aggregate, WIDE-ISSUE: 4 nodes/wave, 2 packets/node/iter ->
//      16 INDEPENDENT row loads consumed in the SAME iteration. No cross-iteration
//      value rotation => nothing to rematerialize (r4/r5 collapse) and no in-flight
//      register copies (r6 crash). Packets are wave-uniform -> s_loads (SGPR). ----
template<int EPI>   // 0: write H + BN stats; 1: pool atomics
__global__ __launch_bounds__(256, 2) void gather(const __half* __restrict__ Ph, __half* H,
    const int2* __restrict__ csr, const int* __restrict__ ebeg, const int* __restrict__ eend,
    float* __restrict__ stats, const int* __restrict__ batch, float* __restrict__ pool)
{
    const unsigned short* __restrict__ P = (const unsigned short*)Ph;
    int t = threadIdx.x, lane = t & 63;
    int wv = __builtin_amdgcn_readfirstlane((blockIdx.x * blockDim.x + t) >> 6);
    int nw = (gridDim.x * blockDim.x) >> 6;
    float s1 = 0.f, s2 = 0.f;
    const int NQ = N / 4;
    for (int g = wv; g < NQ; g += nw) {
        int n0 = 4 * g;
        int b0 = ebeg[n0],     m0 = (eend[n0]     - b0 + 1) >> 1;
        int b1 = ebeg[n0 + 1], m1 = (eend[n0 + 1] - b1 + 1) >> 1;
        int b2 = ebeg[n0 + 2], m2 = (eend[n0 + 2] - b2 + 1) >> 1;
        int b3 = ebeg[n0 + 3], m3 = (eend[n0 + 3] - b3 + 1) >> 1;
        const int4* q0 = (const int4*)csr + (b0 >> 1);
        const int4* q1 = (const int4*)csr + (b1 >> 1);
        const int4* q2 = (const int4*)csr + (b2 >> 1);
        const int4* q3 = (const int4*)csr + (b3 >> 1);
        int c0 = max(m0 - 1, 0), c1 = max(m1 - 1, 0);
        int c2 = max(m2 - 1, 0), c3 = max(m3 - 1, 0);
        float x0 = __half2float(H[(size_t)(n0    ) * 64 + lane]);
        float x1 = __half2float(H[(size_t)(n0 + 1) * 64 + lane]);
        float x2 = __half2float(H[(size_t)(n0 + 2) * 64 + lane]);
        float x3 = __half2float(H[(size_t)(n0 + 3) * 64 + lane]);
        float a00 = 0.f, a01 = 0.f, a02 = 0.f, a03 = 0.f;
        float a10 = 0.f, a11 = 0.f, a12 = 0.f, a13 = 0.f;
        float a20 = 0.f, a21 = 0.f, a22 = 0.f, a23 = 0.f;
        float a30 = 0.f, a31 = 0.f, a32 = 0.f, a33 = 0.f;
        int mm = max(max(m0, m1), max(m2, m3));
        for (int k = 0; k < mm; k += 2) {
            // 8 wave-uniform packets (s_load): packets k and k+1 for each node
            int4 pA0 = q0[min(k, c0)], pB0 = q0[min(k + 1, c0)];
            int4 pA1 = q1[min(k, c1)], pB1 = q1[min(k + 1, c1)];
            int4 pA2 = q2[min(k, c2)], pB2 = q2[min(k + 1, c2)];
            int4 pA3 = q3[min(k, c3)], pB3 = q3[min(k + 1, c3)];
            // 16 independent row loads, all consumed below in this iteration
            unsigned short rA00 = P[(size_t)pA0.x * 64 + lane], rA01 = P[(size_t)pA0.z * 64 + lane];
            unsigned short rB00 = P[(size_t)pB0.x * 64 + lane], rB01 = P[(size_t)pB0.z * 64 + lane];
            unsigned short rA10 = P[(size_t)pA1.x * 64 + lane], rA11 = P[(size_t)pA1.z * 64 + lane];
            unsigned short rB10 = P[(size_t)pB1.x * 64 + lane], rB11 = P[(size_t)pB1.z * 64 + lane];
            unsigned short rA20 = P[(size_t)pA2.x * 64 + lane], rA21 = P[(size_t)pA2.z * 64 + lane];
            unsigned short rB20 = P[(size_t)pB2.x * 64 + lane], rB21 = P[(size_t)pB2.z * 64 + lane];
            unsigned short rA30 = P[(size_t)pA3.x * 64 + lane], rA31 = P[(size_t)pA3.z * 64 + lane];
            unsigned short rB30 = P[(size_t)pB3.x * 64 + lane], rB31 = P[(size_t)pB3.z * 64 + lane];
            float wA00 = (k < m0) ? __int_as_float(pA0.y) : 0.f;
            float wA01 = (k < m0) ? __int_as_float(pA0.w) : 0.f;
            float wB00 = (k + 1 < m0) ? __int_as_float(pB0.y) : 0.f;
            float wB01 = (k + 1 < m0) ? __int_as_float(pB0.w) : 0.f;
            float wA10 = (k < m1) ? __int_as_float(pA1.y) : 0.f;
            float wA11 = (k < m1) ? __int_as_float(pA1.w) : 0.f;
            float wB10 = (k + 1 < m1) ? __int_as_float(pB1.y) : 0.f;
            float wB11 = (k + 1 < m1) ? __int_as_float(pB1.w) : 0.f;
            float wA20 = (k < m2) ? __int_as_float(pA2.y) : 0.f;
            float wA21 = (k < m2) ? __int_as_float(pA2.w) : 0.f;
            float wB20 = (k + 1 < m2) ? __int_as_float(pB2.y) : 0.f;
            float wB21 = (k + 1 < m2) ? __int_as_float(pB2.w) : 0.f;
            float wA30 = (k < m3) ? __int_as_float(pA3.y) : 0.f;
            float wA31 = (k < m3) ? __int_as_float(pA3.w) : 0.f;
            float wB30 = (k + 1 < m3) ? __int_as_float(pB3.y) : 0.f;
            float wB31 = (k + 1 < m3) ? __int_as_float(pB3.w) : 0.f;
            a00 = fmaf(wA00, us2f(rA00), a00); a01 = fmaf(wA01, us2f(rA01), a01);
            a02 = fmaf(wB00, us2f(rB00), a02); a03 = fmaf(wB01, us2f(rB01), a03);
            a10 = fmaf(wA10, us2f(rA10), a10); a11 = fmaf(wA11, us2f(rA11), a11);
            a12 = fmaf(wB10, us2f(rB10), a12); a13 = fmaf(wB11, us2f(rB11), a13);
            a20 = fmaf(wA20, us2f(rA20), a20); a21 = fmaf(wA21, us2f(rA21), a21);
            a22 = fmaf(wB20, us2f(rB20), a22); a23 = fmaf(wB21, us2f(rB21), a23);
            a30 = fmaf(wA30, us2f(rA30), a30); a31 = fmaf(wA31, us2f(rA31), a31);
            a32 = fmaf(wB30, us2f(rB30), a32); a33 = fmaf(wB31, us2f(rB31), a33);
        }
        float r0 = x0 + ((a00 + a02) + (a01 + a03));
        float r1 = x1 + ((a10 + a12) + (a11 + a13));
        float r2 = x2 + ((a20 + a22) + (a21 + a23));
        float r3 = x3 + ((a30 + a32) + (a31 + a33));
        if constexpr (EPI == 0) {
            H[(size_t)(n0    ) * 64 + lane] = __float2half(r0);
            H[(size_t)(n0 + 1) * 64 + lane] = __float2half(r1);
            H[(size_t)(n0 + 2) * 64 + lane] = __float2half(r2);
            H[(size_t)(n0 + 3) * 64 + lane] = __float2half(r3);
            s1 += (r0 + r1) + (r2 + r3);
            s2 += (r0 * r0 + r1 * r1) + (r2 * r2 + r3 * r3);
        } else {
            atomAddF(&pool[batch[n0    ] * 64 + lane], r0);
            atomAddF(&pool[batch[n0 + 1] * 64 + lane], r1);
            atomAddF(&pool[batch[n0 + 2] * 64 + lane], r2);
            atomAddF(&pool[batch[n0 + 3] * 64 + lane], r3);
        }
    }
    if constexpr (EPI == 0) {
        __shared__ float sred[256];
        sred[t] = s1; __syncthreads();
        if (t < 64) atomAddF(&stats[t], sred[t] + sred[t+64] + sred[t+128] + sred[t+192]);
        __syncthreads();
        sred[t] = s2; __syncthreads();
        if (t < 64) atomAddF(&stats[64 + t], sred[t] + sred[t+64] + sred[t+128] + sred[t+192]);
    }
}

// ---- head: mean-pool finalize + 2-layer MLP ----
__global__ __launch_bounds__(64) void head(const float* __restrict__ pool,
    const int* __restrict__ batch, const float* __restrict__ Wl1, const float* __restrict__ bl1,
    const float* __restrict__ Wl2, const float* __restrict__ bl2, float* __restrict__ out)
{
    int g = blockIdx.x, t = threadIdx.x;
    __shared__ float sp[64];
    __shared__ float sz[64];
    __shared__ int scnt;
    if (t == 0) {
        int lo = 0, hi = N;
        while (lo < hi) { int m = (lo + hi) >> 1; if (batch[m] < g) lo = m + 1; else hi = m; }
        int lo2 = lo, hi2 = N;
        while (lo2 < hi2) { int m = (lo2 + hi2) >> 1; if (batch[m] < g + 1) lo2 = m + 1; else hi2 = m; }
        scnt = lo2 - lo;
    }
    __syncthreads();
    float cnt = fmaxf((float)scnt, 1.0f);
    sp[t] = pool[g * 64 + t] / cnt;
    __syncthreads();
    float acc = bl1[t];
#pragma unroll
    for (int k = 0; k < 64; k++) acc = fmaf(sp[k], Wl1[k * 64 + t], acc);
    sz[t] = fmaxf(acc, 0.f);
    __syncthreads();
    if (t < OUTF) {
        float o = bl2[t];
#pragma unroll
        for (int k = 0; k < 64; k++) o = fmaf(sz[k], Wl2[k * OUTF + t], o);
        out[g * OUTF + t] = o;
    }
}

extern "C" void kernel_launch(void* const* d_in, const int* in_sizes, int n_in,
                              void* d_out, int out_size, void* d_ws, size_t ws_size,
                              hipStream_t stream)
{
    const float* x     = (const float*)d_in[0];
    const int*   ei    = (const int*)d_in[1];
    const float* ew    = (const float*)d_in[2];
    const int*   batch = (const int*)d_in[3];
    const float* Wrel0 = (const float*)d_in[4];
    const float* Wroot0= (const float*)d_in[5];
    const float* b0    = (const float*)d_in[6];
    const float* Wrel1 = (const float*)d_in[7];
    const float* Wroot1= (const float*)d_in[8];
    const float* b1    = (const float*)d_in[9];
    const float* Wrel2 = (const float*)d_in[10];
    const float* Wroot2= (const float*)d_in[11];
    const float* b2    = (const float*)d_in[12];
    const float* g0    = (const float*)d_in[13];
    const float* be0   = (const float*)d_in[14];
    const float* g1    = (const float*)d_in[15];
    const float* be1   = (const float*)d_in[16];
    const float* Wl1   = (const float*)d_in[17];
    const float* bl1   = (const float*)d_in[18];
    const float* Wl2   = (const float*)d_in[19];
    const float* bl2   = (const float*)d_in[20];
    const int* srcI = ei;
    const int* dstI = ei + E;

    __half* Ha     = (__half*)d_ws;                    // N*64 fp16
    __half* Hb     = Ha + (size_t)N * 64;              // N*64 fp16
    __half* P      = Hb + (size_t)N * 64;              // N*64 fp16
    int2*   csr    = (int2*)(P + (size_t)N * 64);      // NB*CBCAP int2 (~16 MB)
    int*    ebeg   = (int*)(csr + (size_t)NB * CBCAP); // N
    int*    eend   = ebeg + N;                         // N
    int*    cursor = eend + N;                         // NB
    float*  stats0 = (float*)(cursor + NB);            // 128 -- zero block start
    float*  stats1 = stats0 + 128;                     // 128
    float*  pool   = stats1 + 128;                     // G*64 -- zero block end
    __half* Wt1    = (__half*)(pool + G * 64);         // 128*64
    __half* Wt2    = Wt1 + 128 * 64;                   // 128*64
    float*  agg9   = (float*)(Wt2 + 128 * 64);         // N*9 f32 (3.6 MB)
    __half* x9     = (__half*)(agg9 + (size_t)N * FIN);// N*9 fp16 (1.8 MB)
    int2*   bucketed = (int2*)Ha;                      // NB*BCAP int2 = 15.2MB, aliases Ha+Hb

    // ---- init + CSR build (bucketed arena, by dst) ----
    initK<<<(N * FIN + 255) / 256, 256, 0, stream>>>(cursor, stats0, x, x9);
    passA<<<NCH, 256, 0, stream>>>(srcI, dstI, ew, cursor, bucketed);
    passB<<<NB, NPB, 0, stream>>>(cursor, bucketed, ebeg, eend, csr);
    wprep<<<64, 256, 0, stream>>>(Wrel1, Wroot1, Wrel2, Wroot2, Wt1);

    // ---- layer 0: 9-dim gather (pipelined) then projection ----
    gather9<<<2048, 256, 0, stream>>>(x9, csr, ebeg, eend, agg9);
    proj0post<<<2048, 256, 0, stream>>>(x, agg9, Wrel0, Wroot0, b0, Ha, stats0);

    // ---- layer 1 (BN0+ReLU fused into projm input) ----
    projm<<<1024, 256, 0, stream>>>(Ha, Wt1, b1, stats0, g0, be0, P, Hb);
    gather<0><<<2048, 256, 0, stream>>>(P, Hb, csr, ebeg, eend, stats1, nullptr, nullptr);

    // ---- layer 2 + pooling (BN1+ReLU fused into projm input) ----
    projm<<<1024, 256, 0, stream>>>(Hb, Wt2, b2, stats1, g1, be1, P, Ha);
    gather<1><<<2048, 256, 0, stream>>>(P, Ha, csr, ebeg, eend, nullptr, batch, pool);

    // ---- head ----
    head<<<G, 64, 0, stream>>>(pool, batch, Wl1, bl1, Wl2, bl2, (float*)d_out);
}